// Round 11
// baseline (289.729 us; speedup 1.0000x reference)
//
#include <hip/hip_runtime.h>
#include <hip/hip_bf16.h>
#include <math.h>

#define B_   4
#define N_   4096
#define K_   16
#define DP_  128
#define DM_  256
#define NPTS (B_ * N_)
#define SEG_ 16
#define CAND_ (N_ / SEG_)   // 256 candidates per segment

typedef unsigned int u32;
typedef unsigned short u16;
typedef _Float16 f16;
typedef __attribute__((ext_vector_type(2))) __fp16 h2;     // matches cvt_pkrtz/fdot2 ABI
typedef __attribute__((ext_vector_type(8))) _Float16 f16x8; // MFMA operand
typedef __attribute__((ext_vector_type(4))) float floatx4;

static __device__ __forceinline__ h2 pkrtz(float a, float b) {
    return __builtin_amdgcn_cvt_pkrtz(a, b);
}
static __device__ __forceinline__ u32 asu32(h2 h) { return __builtin_bit_cast(u32, h); }
static __device__ __forceinline__ h2 ash2(u32 u) { return __builtin_bit_cast(h2, u); }

// ---- bitonic primitives on u32 registers ----
#define CEXA(x, y) { u32 _lo = min(x, y); y = max(x, y); x = _lo; }   // x<=y
#define CEXD(x, y) { u32 _hi = max(x, y); y = min(x, y); x = _hi; }   // x>=y

// full bitonic sort of 16, DESCENDING; 80 CEX
static __device__ __forceinline__ void sort16_desc(u32 c[16]) {
    CEXD(c[0],c[1]);  CEXA(c[2],c[3]);  CEXD(c[4],c[5]);  CEXA(c[6],c[7]);
    CEXD(c[8],c[9]);  CEXA(c[10],c[11]); CEXD(c[12],c[13]); CEXA(c[14],c[15]);

    CEXD(c[0],c[2]);  CEXD(c[1],c[3]);  CEXA(c[4],c[6]);  CEXA(c[5],c[7]);
    CEXD(c[8],c[10]); CEXD(c[9],c[11]); CEXA(c[12],c[14]); CEXA(c[13],c[15]);
    CEXD(c[0],c[1]);  CEXD(c[2],c[3]);  CEXA(c[4],c[5]);  CEXA(c[6],c[7]);
    CEXD(c[8],c[9]);  CEXD(c[10],c[11]); CEXA(c[12],c[13]); CEXA(c[14],c[15]);

    CEXD(c[0],c[4]);  CEXD(c[1],c[5]);  CEXD(c[2],c[6]);  CEXD(c[3],c[7]);
    CEXA(c[8],c[12]); CEXA(c[9],c[13]); CEXA(c[10],c[14]); CEXA(c[11],c[15]);
    CEXD(c[0],c[2]);  CEXD(c[1],c[3]);  CEXD(c[4],c[6]);  CEXD(c[5],c[7]);
    CEXA(c[8],c[10]); CEXA(c[9],c[11]); CEXA(c[12],c[14]); CEXA(c[13],c[15]);
    CEXD(c[0],c[1]);  CEXD(c[2],c[3]);  CEXD(c[4],c[5]);  CEXD(c[6],c[7]);
    CEXA(c[8],c[9]);  CEXA(c[10],c[11]); CEXA(c[12],c[13]); CEXA(c[14],c[15]);

    CEXD(c[0],c[8]);  CEXD(c[1],c[9]);  CEXD(c[2],c[10]); CEXD(c[3],c[11]);
    CEXD(c[4],c[12]); CEXD(c[5],c[13]); CEXD(c[6],c[14]); CEXD(c[7],c[15]);
    CEXD(c[0],c[4]);  CEXD(c[1],c[5]);  CEXD(c[2],c[6]);  CEXD(c[3],c[7]);
    CEXD(c[8],c[12]); CEXD(c[9],c[13]); CEXD(c[10],c[14]); CEXD(c[11],c[15]);
    CEXD(c[0],c[2]);  CEXD(c[1],c[3]);  CEXD(c[4],c[6]);  CEXD(c[5],c[7]);
    CEXD(c[8],c[10]); CEXD(c[9],c[11]); CEXD(c[12],c[14]); CEXD(c[13],c[15]);
    CEXD(c[0],c[1]);  CEXD(c[2],c[3]);  CEXD(c[4],c[5]);  CEXD(c[6],c[7]);
    CEXD(c[8],c[9]);  CEXD(c[10],c[11]); CEXD(c[12],c[13]); CEXD(c[14],c[15]);
}

// L is bitonic -> sort ascending; 32 CEX
static __device__ __forceinline__ void remerge16_asc(u32 L[16]) {
    CEXA(L[0],L[8]);  CEXA(L[1],L[9]);  CEXA(L[2],L[10]); CEXA(L[3],L[11]);
    CEXA(L[4],L[12]); CEXA(L[5],L[13]); CEXA(L[6],L[14]); CEXA(L[7],L[15]);
    CEXA(L[0],L[4]);  CEXA(L[1],L[5]);  CEXA(L[2],L[6]);  CEXA(L[3],L[7]);
    CEXA(L[8],L[12]); CEXA(L[9],L[13]); CEXA(L[10],L[14]); CEXA(L[11],L[15]);
    CEXA(L[0],L[2]);  CEXA(L[1],L[3]);  CEXA(L[4],L[6]);  CEXA(L[5],L[7]);
    CEXA(L[8],L[10]); CEXA(L[9],L[11]); CEXA(L[12],L[14]); CEXA(L[13],L[15]);
    CEXA(L[0],L[1]);  CEXA(L[2],L[3]);  CEXA(L[4],L[5]);  CEXA(L[6],L[7]);
    CEXA(L[8],L[9]);  CEXA(L[10],L[11]); CEXA(L[12],L[13]); CEXA(L[14],L[15]);
}

// ---------------- KNN phase 1: bitonic-batch top-16 per (point, segment) ----------------
__global__ __launch_bounds__(256, 1) void knn_part_kernel(const float* __restrict__ xyz,
                                                          u32* __restrict__ part)
{
    const int b = blockIdx.z;
    const int s = blockIdx.y;
    const int n = blockIdx.x * 256 + threadIdx.x;
    const float* xb = xyz + (size_t)b * N_ * 3;
    const float xn0 = xb[n * 3 + 0], xn1 = xb[n * 3 + 1], xn2 = xb[n * 3 + 2];
    const float sqn = xn0 * xn0 + xn1 * xn1 + xn2 * xn2;

    __shared__ float4 sc[CAND_];
    {
        const int m = s * CAND_ + threadIdx.x;   // CAND_ == 256 == blockDim.x
        const float a0 = xb[m * 3 + 0];
        const float a1 = xb[m * 3 + 1];
        const float a2 = xb[m * 3 + 2];
        sc[threadIdx.x] = make_float4(a0, a1, a2, a0 * a0 + a1 * a1 + a2 * a2);
    }
    __syncthreads();

    u32 L[16];
#pragma unroll
    for (int i = 0; i < 16; ++i) L[i] = 0xFFFFFFFFu;

    const u32 ibase = (u32)(s * CAND_);
    for (int m0 = 0; m0 < CAND_; m0 += 16) {
        u32 c[16];
#pragma unroll
        for (int t = 0; t < 16; ++t) {
            const float4 cc = sc[m0 + t];
            const float dot = xn0 * cc.x + xn1 * cc.y + xn2 * cc.z;
            const float d = (sqn + cc.w) - 2.0f * dot;
            const int ib = __float_as_int(d);
            const u32 tk = (u32)ib ^ (u32)((ib >> 31) | 0x80000000);
            c[t] = (tk & 0xFFFFF000u) | (ibase + (u32)(m0 + t));
        }
        sort16_desc(c);
#pragma unroll
        for (int i = 0; i < 16; ++i) L[i] = min(L[i], c[i]);
        remerge16_asc(L);
    }

    const int p = b * N_ + n;
#pragma unroll
    for (int j = 0; j < 16; ++j)
        part[(size_t)(s * 16 + j) * NPTS + p] = L[j];
}

// ---------------- KNN merge stage A: 4 segments -> 1 sorted list (x4 groups) ----------------
__global__ __launch_bounds__(256, 1) void knn_mergeA_kernel(const u32* __restrict__ part,
                                                            u32* __restrict__ m4)
{
    const int g = blockIdx.y;                                // group 0..3
    const int p = blockIdx.x * 256 + threadIdx.x;            // global point id

    u32 L[16];
#pragma unroll
    for (int i = 0; i < 16; ++i) L[i] = 0xFFFFFFFFu;

    for (int s = g * 4; s < g * 4 + 4; ++s) {
        u32 seg[16];
#pragma unroll
        for (int j = 0; j < 16; ++j)
            seg[j] = part[(size_t)(s * 16 + j) * NPTS + p];
#pragma unroll
        for (int i = 0; i < 16; ++i) L[i] = min(L[i], seg[15 - i]);
        remerge16_asc(L);
    }
#pragma unroll
    for (int j = 0; j < 16; ++j)
        m4[(size_t)(g * 16 + j) * NPTS + p] = L[j];
}

// ---------------- KNN merge stage B: 4 sorted lists -> final top-16 indices ----------------
__global__ __launch_bounds__(256, 1) void knn_mergeB_kernel(const u32* __restrict__ m4,
                                                            int* __restrict__ knn_idx)
{
    const int p = blockIdx.x * 256 + threadIdx.x;
    const int b = p >> 12;

    u32 L[16];
#pragma unroll
    for (int i = 0; i < 16; ++i) L[i] = 0xFFFFFFFFu;

    for (int g = 0; g < 4; ++g) {
        u32 seg[16];
#pragma unroll
        for (int j = 0; j < 16; ++j)
            seg[j] = m4[(size_t)(g * 16 + j) * NPTS + p];
#pragma unroll
        for (int i = 0; i < 16; ++i) L[i] = min(L[i], seg[15 - i]);
        remerge16_asc(L);
    }

    int* o = knn_idx + (size_t)p * K_;
#pragma unroll
    for (int i = 0; i < 16; ++i) o[i] = b * N_ + (int)(L[i] & 0xFFFu);
}

// ---------------- f16 MFMA GEMM: C[M,N] = A[M,K] @ Bt[N,K]^T (+bias +addC) ----------------
// CT != null: store TRANSPOSED to [B][DP][N] fp32 (fused output transpose).
__global__ __launch_bounds__(256) void gemm_f16_kernel(
    const f16* __restrict__ A,     // [M][K]
    const f16* __restrict__ Bt,    // [N][K]
    const float* __restrict__ bias,
    const float* __restrict__ addC,   // fp32, row stride ldc
    float* __restrict__ CT,        // transposed fp32 out [B][DP][N], or null
    f16* __restrict__ Cb,          // f16 out, row stride ldc, or null
    int M, int N, int K, int ldc)
{
    __shared__ __align__(16) f16 As[128 * 32];
    __shared__ __align__(16) f16 Bs[128 * 32];
    const int tid = threadIdx.x;
    const int m0 = blockIdx.y * 128, n0 = blockIdx.x * 128;
    const int w = tid >> 6, l = tid & 63;
    const int wm = (w >> 1) * 64, wn = (w & 1) * 64;
    const int fm = l & 15, kq = l >> 4;

    floatx4 acc[4][4];
#pragma unroll
    for (int i = 0; i < 4; ++i)
#pragma unroll
        for (int j = 0; j < 4; ++j)
            acc[i][j] = (floatx4){0.0f, 0.0f, 0.0f, 0.0f};

    for (int k0 = 0; k0 < K; k0 += 32) {
        __syncthreads();
#pragma unroll
        for (int c = 0; c < 2; ++c) {
            const int li = tid + c * 256;
            const int row = li >> 2, part = li & 3;
            *(uint4*)&As[row * 32 + part * 8] =
                *(const uint4*)&A[(size_t)(m0 + row) * K + k0 + part * 8];
            *(uint4*)&Bs[row * 32 + part * 8] =
                *(const uint4*)&Bt[(size_t)(n0 + row) * K + k0 + part * 8];
        }
        __syncthreads();
        f16x8 af[4], bf[4];
#pragma unroll
        for (int i = 0; i < 4; ++i)
            af[i] = *(const f16x8*)&As[(wm + i * 16 + fm) * 32 + kq * 8];
#pragma unroll
        for (int j = 0; j < 4; ++j)
            bf[j] = *(const f16x8*)&Bs[(wn + j * 16 + fm) * 32 + kq * 8];
#pragma unroll
        for (int i = 0; i < 4; ++i)
#pragma unroll
            for (int j = 0; j < 4; ++j)
                acc[i][j] = __builtin_amdgcn_mfma_f32_16x16x32_f16(af[i], bf[j], acc[i][j], 0, 0, 0);
    }

#pragma unroll
    for (int i = 0; i < 4; ++i) {
#pragma unroll
        for (int j = 0; j < 4; ++j) {
            const int col = n0 + wn + j * 16 + fm;
            const int rowb = m0 + wm + i * 16 + kq * 4;
            float4 vv;
#pragma unroll
            for (int r = 0; r < 4; ++r) {
                const int m = rowb + r;
                float v = acc[i][j][r];
                if (bias) v += bias[col];
                if (addC) v += addC[(size_t)m * ldc + col];
                ((float*)&vv)[r] = v;
            }
            if (CT) {   // rows rowb..rowb+3 are consecutive n within one batch
                const int bb = rowb >> 12;
                *(float4*)&CT[(size_t)(bb * DP_ + col) * N_ + (rowb & (N_ - 1))] = vv;
            } else if (Cb) {
#pragma unroll
                for (int r = 0; r < 4; ++r)
                    Cb[(size_t)(rowb + r) * ldc + col] = (f16)((float*)&vv)[r];
            }
        }
    }
}

// ---------------- one-shot prep: weight transpose-casts + straight casts (f16) ----------------
// k/v rows of catW INTERLEAVED: k-col c -> row 256+8*(c/4)+(c%4); v-col c -> +4.
__global__ __launch_bounds__(256) void prep_kernel(
    const float* __restrict__ wq, const float* __restrict__ wk, const float* __restrict__ wv,
    const float* __restrict__ fd2, const float* __restrict__ fc1, const float* __restrict__ fc2,
    const float* __restrict__ feat,
    f16* __restrict__ catW, f16* __restrict__ fc2T, f16* __restrict__ bt2,
    f16* __restrict__ fd2c, f16* __restrict__ wqc, f16* __restrict__ fc1c,
    f16* __restrict__ featb)
{
    __shared__ float t[32][33];
    const int job = blockIdx.z;
    const int tid = threadIdx.x;

    if (job < 4) {
        const float* in; int R, C;
        switch (job) {
            case 0: in = wq;  R = DM_; C = DM_; break;
            case 1: in = wk;  R = DM_; C = DM_; break;
            case 2: in = wv;  R = DM_; C = DM_; break;
            default: in = fc2; R = DM_; C = DP_; break;
        }
        const int c0 = blockIdx.x * 32, r0 = blockIdx.y * 32;
        if (c0 >= C || r0 >= R) return;
        const int lx = tid & 31, ly = tid >> 5;
#pragma unroll
        for (int i = 0; i < 32; i += 8)
            t[ly + i][lx] = in[(size_t)(r0 + ly + i) * C + c0 + lx];
        __syncthreads();
#pragma unroll
        for (int i = 0; i < 32; i += 8) {
            const int c = c0 + ly + i;
            const f16 v = (f16)t[lx][ly + i];
            int n;
            switch (job) {
                case 0: n = c; break;
                case 1: n = 256 + ((c >> 2) << 3) + (c & 3); break;
                case 2: n = 256 + ((c >> 2) << 3) + 4 + (c & 3); break;
                default: n = -1; break;
            }
            if (job < 3) {
                catW[(size_t)n * DM_ + r0 + lx] = v;
            } else {
                fc2T[(size_t)c * DM_ + r0 + lx] = v;
                bt2[(size_t)c * 512 + 256 + r0 + lx] = v;
            }
        }
    } else {
        const int bid = blockIdx.y * 8 + blockIdx.x;
        const int tId = bid * 256 + tid;
        const float* in; f16* outp; int n4;
        if (job == 4)      { in = fd2;  outp = fd2c;  n4 = (DM_ * DM_) / 4; }
        else if (job == 5) { in = wq;   outp = wqc;   n4 = (DM_ * DM_) / 4; }
        else if (job == 6) { in = fc1;  outp = fc1c;  n4 = (DP_ * DM_) / 4; }
        else               { in = feat; outp = featb; n4 = (NPTS * DP_) / 4; }
        for (int i = tId; i < n4; i += 16384) {
            const float4 v = ((const float4*)in)[i];
            const u32 lo = asu32(pkrtz(v.x, v.y));
            const u32 hi = asu32(pkrtz(v.z, v.w));
            ((uint2*)outp)[i] = make_uint2(lo, hi);
        }
    }
}

// ---------------- folded bias vectors ----------------
__global__ __launch_bounds__(256) void bias_kernel(
    const float* __restrict__ fc1_b, const float* __restrict__ fd2_b,
    const float* __restrict__ fc2_w, const float* __restrict__ fc2_b,
    const f16* __restrict__ catW,
    float* __restrict__ b_all, float* __restrict__ bias2)
{
    const int tid = threadIdx.x;
    if (blockIdx.x < 4) {
        const int n = blockIdx.x * 256 + tid;
        float s = 0.0f;
        for (int j = 0; j < DM_; ++j)
            s += fc1_b[j] * (float)catW[(size_t)n * DM_ + j];
        b_all[n] = s;
    } else if (tid < DP_) {
        float s = fc2_b[tid];
        for (int t = 0; t < DM_; ++t)
            s += fd2_b[t] * fc2_w[(size_t)t * DP_ + tid];
        bias2[tid] = s;
    }
}

// ---------------- fused attention: one WAVE per point; ALL 16 kv rows prefetched ----------------
// qkv row p (stride 1024 f16): [0,256)=q, [256,768)=interleaved {k[4c..],v[4c..]} octets,
// [768,1024)=qp.  Lane l owns dims 4l..4l+3: k AND v halves arrive in ONE uint4, and all
// 16 neighbor rows are loaded back-to-back (64 VGPRs) so ~16 gathers stay in flight
// (round 10: VGPR=76 capped MLP at ~2-3 -> latency-bound at 52 us).
__global__ __launch_bounds__(256) void attn_kernel(
    const float* __restrict__ xyz, const f16* __restrict__ qkv,
    const int* __restrict__ knn_idx,
    const float* __restrict__ fd1_w, const float* __restrict__ fd1_b,
    const float* __restrict__ fd2_b,
    f16* __restrict__ ab)
{
    const int wave = threadIdx.x >> 6, l = threadIdx.x & 63;
    const int p = blockIdx.x * 4 + wave;
    const int c0 = l * 4;

    int gi = 0; float dx = 0.0f, dy = 0.0f, dz = 0.0f;
    if (l < 16) {
        gi = knn_idx[p * K_ + l];
        dx = xyz[(size_t)p * 3 + 0] - xyz[(size_t)gi * 3 + 0];
        dy = xyz[(size_t)p * 3 + 1] - xyz[(size_t)gi * 3 + 1];
        dz = xyz[(size_t)p * 3 + 2] - xyz[(size_t)gi * 3 + 2];
    }

    // prefetch ALL 16 neighbor kv rows (independent 16B loads, stay in flight)
    uint4 kvr[16];
#pragma unroll
    for (int k = 0; k < 16; ++k) {
        const int gik = __shfl(gi, k);
        kvr[k] = *(const uint4*)(qkv + (size_t)gik * 1024 + 256 + l * 8);
    }

    const uint2 qu  = *(const uint2*)(qkv + (size_t)p * 1024 + c0);
    const uint2 qpu = *(const uint2*)(qkv + (size_t)p * 1024 + 768 + c0);
    const h2 q01 = ash2(qu.x), q23 = ash2(qu.y);
    const h2 qp01 = ash2(qpu.x), qp23 = ash2(qpu.y);

    const float4 w0 = *(const float4*)&fd1_w[c0];
    const float4 w1 = *(const float4*)&fd1_w[DM_ + c0];
    const float4 w2 = *(const float4*)&fd1_w[2 * DM_ + c0];
    const float4 b1 = *(const float4*)&fd1_b[c0];
    const float4 f2b = *(const float4*)&fd2_b[c0];
    const h2 f2b01 = pkrtz(f2b.x, f2b.y);
    const h2 f2b23 = pkrtz(f2b.z, f2b.w);

    // qb = q . fd2_b (constant over k)
    float qb;
    {
        float tq = __builtin_amdgcn_fdot2(q01, f2b01, 0.0f, false);
        tq = __builtin_amdgcn_fdot2(q23, f2b23, tq, false);
#pragma unroll
        for (int off = 1; off < 64; off <<= 1) tq += __shfl_xor(tq, off);
        qb = tq;
    }

    // phase 1: logits via f16 dot2; packed h kept in regs for phase 2
    float lg[16];
    u32 h01r[16], h23r[16];
#pragma unroll
    for (int k = 0; k < 16; ++k) {
        const float d0 = __shfl(dx, k), d1 = __shfl(dy, k), d2 = __shfl(dz, k);
        const float h0 = fmaxf(d0 * w0.x + d1 * w1.x + d2 * w2.x + b1.x, 0.0f);
        const float h1 = fmaxf(d0 * w0.y + d1 * w1.y + d2 * w2.y + b1.y, 0.0f);
        const float h2v = fmaxf(d0 * w0.z + d1 * w1.z + d2 * w2.z + b1.z, 0.0f);
        const float h3 = fmaxf(d0 * w0.w + d1 * w1.w + d2 * w2.w + b1.w, 0.0f);
        const h2 hp01 = pkrtz(h0, h1);
        const h2 hp23 = pkrtz(h2v, h3);
        h01r[k] = asu32(hp01); h23r[k] = asu32(hp23);
        float t = __builtin_amdgcn_fdot2(ash2(kvr[k].x), q01, 0.0f, false);
        t = __builtin_amdgcn_fdot2(ash2(kvr[k].y), q23, t, false);
        t = __builtin_amdgcn_fdot2(hp01, qp01, t, false);
        t = __builtin_amdgcn_fdot2(hp23, qp23, t, false);
#pragma unroll
        for (int off = 1; off < 64; off <<= 1) t += __shfl_xor(t, off);
        lg[k] = t;
    }

    // softmax over 16 (redundant per lane, all registers)
    float att[16];
    {
        float mx = -3.0e38f;
#pragma unroll
        for (int k = 0; k < 16; ++k) {
            att[k] = (lg[k] + qb) * (1.0f / 16.0f);
            mx = fmaxf(mx, att[k]);
        }
        float s = 0.0f;
#pragma unroll
        for (int k = 0; k < 16; ++k) { att[k] = __expf(att[k] - mx); s += att[k]; }
        const float inv = 1.0f / s;
#pragma unroll
        for (int k = 0; k < 16; ++k) att[k] *= inv;
    }

    // phase 2: pure VALU — rbar = sum att*v (kvr regs), hbar = sum att*h (regs)
    float rb[4] = {0, 0, 0, 0}, hb[4] = {0, 0, 0, 0};
#pragma unroll
    for (int k = 0; k < 16; ++k) {
        const h2 v01 = ash2(kvr[k].z), v23 = ash2(kvr[k].w);
        const h2 hh01 = ash2(h01r[k]), hh23 = ash2(h23r[k]);
        const float a = att[k];
        rb[0] = fmaf(a, (float)v01.x, rb[0]);
        rb[1] = fmaf(a, (float)v01.y, rb[1]);
        rb[2] = fmaf(a, (float)v23.x, rb[2]);
        rb[3] = fmaf(a, (float)v23.y, rb[3]);
        hb[0] = fmaf(a, (float)hh01.x, hb[0]);
        hb[1] = fmaf(a, (float)hh01.y, hb[1]);
        hb[2] = fmaf(a, (float)hh23.x, hb[2]);
        hb[3] = fmaf(a, (float)hh23.y, hb[3]);
    }

    const uint2 ho = make_uint2(asu32(pkrtz(hb[0], hb[1])), asu32(pkrtz(hb[2], hb[3])));
    const uint2 ro = make_uint2(asu32(pkrtz(rb[0], rb[1])), asu32(pkrtz(rb[2], rb[3])));
    *(uint2*)(ab + (size_t)p * 512 + c0) = ho;
    *(uint2*)(ab + (size_t)p * 512 + 256 + c0) = ro;
}

extern "C" void kernel_launch(void* const* d_in, const int* in_sizes, int n_in,
                              void* d_out, int out_size, void* d_ws, size_t ws_size,
                              hipStream_t stream)
{
    const float* features = (const float*)d_in[0];
    const float* xyz   = (const float*)d_in[1];
    const float* fc1_w = (const float*)d_in[2];
    const float* fc1_b = (const float*)d_in[3];
    const float* fc2_w = (const float*)d_in[4];
    const float* fc2_b = (const float*)d_in[5];
    const float* fd1_w = (const float*)d_in[6];
    const float* fd1_b = (const float*)d_in[7];
    const float* fd2_w = (const float*)d_in[8];
    const float* fd2_b = (const float*)d_in[9];
    const float* wq    = (const float*)d_in[10];
    const float* wk    = (const float*)d_in[11];
    const float* wv    = (const float*)d_in[12];
    float* out = (float*)d_out;

    char* base = (char*)d_ws;
    const size_t MB = 1024 * 1024;
    u32*  part = (u32*)(base + 0);                 // 16 MB (16 segs), dead after mergeA
    f16*  ab   = (f16*)(base + 0);                 // 16 MB [hbar|rbar]
    u32*  m4   = (u32*)(base + 16 * MB);           // 4 MB (4 lists), dead after mergeB
    f16*  qkv  = (f16*)(base + 36 * MB);           // 32 MB
    f16*  featb = (f16*)(base + 68 * MB);          // 4 MB
    int*  idx  = (int*)(base + 72 * MB);           // 1 MB
    char* wb = base + 73 * MB;
    f16* catW  = (f16*)(wb + 0);                   // [1024][256] = 512 KB
    f16* WallT = (f16*)(wb + 512 * 1024);          // [1024][128] = 256 KB
    f16* bt2   = (f16*)(wb + 768 * 1024);          // [128][512]  = 128 KB
    f16* fd2c  = (f16*)(wb + 896 * 1024);
    f16* wqc   = (f16*)(wb + 1024 * 1024);
    f16* fc1c  = (f16*)(wb + 1152 * 1024);
    f16* fc2T  = (f16*)(wb + 1216 * 1024);
    float* b_all = (float*)(wb + 1280 * 1024);
    float* bias2 = (float*)(wb + 1284 * 1024);

    const dim3 blk(256);

    // casts (also seeds bt2 cols [256,512) with fc2^T); k/v rows interleaved in catW
    prep_kernel<<<dim3(8, 8, 8), blk, 0, stream>>>(wq, wk, wv, fd2_w, fc1_w, fc2_w, features,
                                                   catW, fc2T, bt2, fd2c, wqc, fc1c, featb);
    // catW rows 768..1023: Wqp^T[a][b] = sum_j fd2[a][j]*wq[b][j]
    gemm_f16_kernel<<<dim3(2, 2), blk, 0, stream>>>(
        fd2c, wqc, nullptr, nullptr, nullptr, catW + 768 * 256, DM_, DM_, DM_, DM_);
    // folded biases
    bias_kernel<<<dim3(5), blk, 0, stream>>>(fc1_b, fd2_b, fc2_w, fc2_b, catW, b_all, bias2);
    // WallT[n][k] = sum_j catW[n][j]*fc1_w[k][j]
    gemm_f16_kernel<<<dim3(1, 8), blk, 0, stream>>>(
        catW, fc1c, nullptr, nullptr, nullptr, WallT, 1024, DP_, DM_, DP_);
    // bt2 cols [0,256): Wof^T[n][j] = sum_t fc2[t][n]*fd2[j][t]
    gemm_f16_kernel<<<dim3(2, 1), blk, 0, stream>>>(
        fc2T, fd2c, nullptr, nullptr, nullptr, bt2, DP_, DM_, DM_, 512);

    // KNN: 16 segments, two-stage merge (A: 1024 waves, B: 256 waves)
    knn_part_kernel<<<dim3(N_ / 256, SEG_, B_), blk, 0, stream>>>(xyz, part);
    knn_mergeA_kernel<<<dim3(NPTS / 256, 4), blk, 0, stream>>>(part, m4);
    knn_mergeB_kernel<<<dim3(NPTS / 256), blk, 0, stream>>>(m4, idx);

    // [q | kv-interleaved | qp] = features @ WallT^T + b_all
    gemm_f16_kernel<<<dim3(1024 / 128, NPTS / 128), blk, 0, stream>>>(
        featb, WallT, b_all, nullptr, nullptr, qkv, NPTS, 1024, DP_, 1024);

    // fused attention -> ab = [hbar | rbar]
    attn_kernel<<<dim3(NPTS / 4), blk, 0, stream>>>(xyz, qkv, idx, fd1_w, fd1_b, fd2_b, ab);

    // out = ab @ bt2^T + bias2 + features, stored TRANSPOSED directly to d_out
    gemm_f16_kernel<<<dim3(1, NPTS / 128), blk, 0, stream>>>(
        ab, bt2, bias2, features, out, nullptr, NPTS, DP_, 512, DP_);

    (void)in_sizes; (void)n_in; (void)out_size; (void)ws_size;
}

// Round 12
// 289.113 us; speedup vs baseline: 1.0021x; 1.0021x over previous
//
#include <hip/hip_runtime.h>
#include <hip/hip_bf16.h>
#include <math.h>

#define B_   4
#define N_   4096
#define K_   16
#define DP_  128
#define DM_  256
#define NPTS (B_ * N_)
#define SEG_ 16
#define CAND_ (N_ / SEG_)   // 256 candidates per segment

typedef unsigned int u32;
typedef unsigned short u16;
typedef _Float16 f16;
typedef __attribute__((ext_vector_type(2))) __fp16 h2;     // matches cvt_pkrtz/fdot2 ABI
typedef __attribute__((ext_vector_type(8))) _Float16 f16x8; // MFMA operand
typedef __attribute__((ext_vector_type(4))) float floatx4;

static __device__ __forceinline__ h2 pkrtz(float a, float b) {
    return __builtin_amdgcn_cvt_pkrtz(a, b);
}
static __device__ __forceinline__ u32 asu32(h2 h) { return __builtin_bit_cast(u32, h); }
static __device__ __forceinline__ h2 ash2(u32 u) { return __builtin_bit_cast(h2, u); }

// ---- bitonic primitives on u32 registers ----
#define CEXA(x, y) { u32 _lo = min(x, y); y = max(x, y); x = _lo; }   // x<=y
#define CEXD(x, y) { u32 _hi = max(x, y); y = min(x, y); x = _hi; }   // x>=y

// full bitonic sort of 16, DESCENDING; 80 CEX
static __device__ __forceinline__ void sort16_desc(u32 c[16]) {
    CEXD(c[0],c[1]);  CEXA(c[2],c[3]);  CEXD(c[4],c[5]);  CEXA(c[6],c[7]);
    CEXD(c[8],c[9]);  CEXA(c[10],c[11]); CEXD(c[12],c[13]); CEXA(c[14],c[15]);

    CEXD(c[0],c[2]);  CEXD(c[1],c[3]);  CEXA(c[4],c[6]);  CEXA(c[5],c[7]);
    CEXD(c[8],c[10]); CEXD(c[9],c[11]); CEXA(c[12],c[14]); CEXA(c[13],c[15]);
    CEXD(c[0],c[1]);  CEXD(c[2],c[3]);  CEXA(c[4],c[5]);  CEXA(c[6],c[7]);
    CEXD(c[8],c[9]);  CEXD(c[10],c[11]); CEXA(c[12],c[13]); CEXA(c[14],c[15]);

    CEXD(c[0],c[4]);  CEXD(c[1],c[5]);  CEXD(c[2],c[6]);  CEXD(c[3],c[7]);
    CEXA(c[8],c[12]); CEXA(c[9],c[13]); CEXA(c[10],c[14]); CEXA(c[11],c[15]);
    CEXD(c[0],c[2]);  CEXD(c[1],c[3]);  CEXD(c[4],c[6]);  CEXD(c[5],c[7]);
    CEXA(c[8],c[10]); CEXA(c[9],c[11]); CEXA(c[12],c[14]); CEXA(c[13],c[15]);
    CEXD(c[0],c[1]);  CEXD(c[2],c[3]);  CEXD(c[4],c[5]);  CEXD(c[6],c[7]);
    CEXA(c[8],c[9]);  CEXA(c[10],c[11]); CEXA(c[12],c[13]); CEXA(c[14],c[15]);

    CEXD(c[0],c[8]);  CEXD(c[1],c[9]);  CEXD(c[2],c[10]); CEXD(c[3],c[11]);
    CEXD(c[4],c[12]); CEXD(c[5],c[13]); CEXD(c[6],c[14]); CEXD(c[7],c[15]);
    CEXD(c[0],c[4]);  CEXD(c[1],c[5]);  CEXD(c[2],c[6]);  CEXD(c[3],c[7]);
    CEXD(c[8],c[12]); CEXD(c[9],c[13]); CEXD(c[10],c[14]); CEXD(c[11],c[15]);
    CEXD(c[0],c[2]);  CEXD(c[1],c[3]);  CEXD(c[4],c[6]);  CEXD(c[5],c[7]);
    CEXD(c[8],c[10]); CEXD(c[9],c[11]); CEXD(c[12],c[14]); CEXD(c[13],c[15]);
    CEXD(c[0],c[1]);  CEXD(c[2],c[3]);  CEXD(c[4],c[5]);  CEXD(c[6],c[7]);
    CEXD(c[8],c[9]);  CEXD(c[10],c[11]); CEXD(c[12],c[13]); CEXD(c[14],c[15]);
}

// L is bitonic -> sort ascending; 32 CEX
static __device__ __forceinline__ void remerge16_asc(u32 L[16]) {
    CEXA(L[0],L[8]);  CEXA(L[1],L[9]);  CEXA(L[2],L[10]); CEXA(L[3],L[11]);
    CEXA(L[4],L[12]); CEXA(L[5],L[13]); CEXA(L[6],L[14]); CEXA(L[7],L[15]);
    CEXA(L[0],L[4]);  CEXA(L[1],L[5]);  CEXA(L[2],L[6]);  CEXA(L[3],L[7]);
    CEXA(L[8],L[12]); CEXA(L[9],L[13]); CEXA(L[10],L[14]); CEXA(L[11],L[15]);
    CEXA(L[0],L[2]);  CEXA(L[1],L[3]);  CEXA(L[4],L[6]);  CEXA(L[5],L[7]);
    CEXA(L[8],L[10]); CEXA(L[9],L[11]); CEXA(L[12],L[14]); CEXA(L[13],L[15]);
    CEXA(L[0],L[1]);  CEXA(L[2],L[3]);  CEXA(L[4],L[5]);  CEXA(L[6],L[7]);
    CEXA(L[8],L[9]);  CEXA(L[10],L[11]); CEXA(L[12],L[13]); CEXA(L[14],L[15]);
}

// ---------------- KNN phase 1: bitonic-batch top-16 per (point, segment) ----------------
// Rank key: e = 0.5*|c|^2 - dot(x_n, c)  — per-thread ordering identical to d2
// (d2 = 2e + sqn, monotone shift), tie-break by idx unchanged.
__global__ __launch_bounds__(256, 1) void knn_part_kernel(const float* __restrict__ xyz,
                                                          u32* __restrict__ part)
{
    const int b = blockIdx.z;
    const int s = blockIdx.y;
    const int n = blockIdx.x * 256 + threadIdx.x;
    const float* xb = xyz + (size_t)b * N_ * 3;
    const float xn0 = xb[n * 3 + 0], xn1 = xb[n * 3 + 1], xn2 = xb[n * 3 + 2];

    __shared__ float4 sc[CAND_];
    {
        const int m = s * CAND_ + threadIdx.x;   // CAND_ == 256 == blockDim.x
        const float a0 = xb[m * 3 + 0];
        const float a1 = xb[m * 3 + 1];
        const float a2 = xb[m * 3 + 2];
        sc[threadIdx.x] = make_float4(a0, a1, a2, 0.5f * (a0 * a0 + a1 * a1 + a2 * a2));
    }
    __syncthreads();

    u32 L[16];
#pragma unroll
    for (int i = 0; i < 16; ++i) L[i] = 0xFFFFFFFFu;

    const u32 ibase = (u32)(s * CAND_);
    for (int m0 = 0; m0 < CAND_; m0 += 16) {
        u32 c[16];
#pragma unroll
        for (int t = 0; t < 16; ++t) {
            const float4 cc = sc[m0 + t];
            const float dot = xn0 * cc.x + xn1 * cc.y + xn2 * cc.z;
            const float e = cc.w - dot;
            const int ib = __float_as_int(e);
            const u32 tk = (u32)ib ^ (u32)((ib >> 31) | 0x80000000);
            c[t] = (tk & 0xFFFFF000u) | (ibase + (u32)(m0 + t));
        }
        sort16_desc(c);
#pragma unroll
        for (int i = 0; i < 16; ++i) L[i] = min(L[i], c[i]);
        remerge16_asc(L);
    }

    const int p = b * N_ + n;
#pragma unroll
    for (int j = 0; j < 16; ++j)
        part[(size_t)(s * 16 + j) * NPTS + p] = L[j];
}

// ---------------- KNN merge stage A: 4 segments -> 1 sorted list (x4 groups) ----------------
__global__ __launch_bounds__(256, 1) void knn_mergeA_kernel(const u32* __restrict__ part,
                                                            u32* __restrict__ m4)
{
    const int g = blockIdx.y;                                // group 0..3
    const int p = blockIdx.x * 256 + threadIdx.x;            // global point id

    u32 L[16];
#pragma unroll
    for (int i = 0; i < 16; ++i) L[i] = 0xFFFFFFFFu;

    for (int s = g * 4; s < g * 4 + 4; ++s) {
        u32 seg[16];
#pragma unroll
        for (int j = 0; j < 16; ++j)
            seg[j] = part[(size_t)(s * 16 + j) * NPTS + p];
#pragma unroll
        for (int i = 0; i < 16; ++i) L[i] = min(L[i], seg[15 - i]);
        remerge16_asc(L);
    }
#pragma unroll
    for (int j = 0; j < 16; ++j)
        m4[(size_t)(g * 16 + j) * NPTS + p] = L[j];
}

// ---------------- KNN merge stage B: 4 sorted lists -> final top-16 indices ----------------
__global__ __launch_bounds__(256, 1) void knn_mergeB_kernel(const u32* __restrict__ m4,
                                                            int* __restrict__ knn_idx)
{
    const int p = blockIdx.x * 256 + threadIdx.x;
    const int b = p >> 12;

    u32 L[16];
#pragma unroll
    for (int i = 0; i < 16; ++i) L[i] = 0xFFFFFFFFu;

    for (int g = 0; g < 4; ++g) {
        u32 seg[16];
#pragma unroll
        for (int j = 0; j < 16; ++j)
            seg[j] = m4[(size_t)(g * 16 + j) * NPTS + p];
#pragma unroll
        for (int i = 0; i < 16; ++i) L[i] = min(L[i], seg[15 - i]);
        remerge16_asc(L);
    }

    int* o = knn_idx + (size_t)p * K_;
#pragma unroll
    for (int i = 0; i < 16; ++i) o[i] = b * N_ + (int)(L[i] & 0xFFFu);
}

// ---------------- f16 MFMA GEMM: C[M,N] = A[M,K] @ Bt[N,K]^T (+bias +addC) ----------------
// CT != null: store TRANSPOSED to [B][DP][N] fp32 (fused output transpose).
__global__ __launch_bounds__(256) void gemm_f16_kernel(
    const f16* __restrict__ A,     // [M][K]
    const f16* __restrict__ Bt,    // [N][K]
    const float* __restrict__ bias,
    const float* __restrict__ addC,   // fp32, row stride ldc
    float* __restrict__ CT,        // transposed fp32 out [B][DP][N], or null
    f16* __restrict__ Cb,          // f16 out, row stride ldc, or null
    int M, int N, int K, int ldc)
{
    __shared__ __align__(16) f16 As[128 * 32];
    __shared__ __align__(16) f16 Bs[128 * 32];
    const int tid = threadIdx.x;
    const int m0 = blockIdx.y * 128, n0 = blockIdx.x * 128;
    const int w = tid >> 6, l = tid & 63;
    const int wm = (w >> 1) * 64, wn = (w & 1) * 64;
    const int fm = l & 15, kq = l >> 4;

    floatx4 acc[4][4];
#pragma unroll
    for (int i = 0; i < 4; ++i)
#pragma unroll
        for (int j = 0; j < 4; ++j)
            acc[i][j] = (floatx4){0.0f, 0.0f, 0.0f, 0.0f};

    for (int k0 = 0; k0 < K; k0 += 32) {
        __syncthreads();
#pragma unroll
        for (int c = 0; c < 2; ++c) {
            const int li = tid + c * 256;
            const int row = li >> 2, part = li & 3;
            *(uint4*)&As[row * 32 + part * 8] =
                *(const uint4*)&A[(size_t)(m0 + row) * K + k0 + part * 8];
            *(uint4*)&Bs[row * 32 + part * 8] =
                *(const uint4*)&Bt[(size_t)(n0 + row) * K + k0 + part * 8];
        }
        __syncthreads();
        f16x8 af[4], bf[4];
#pragma unroll
        for (int i = 0; i < 4; ++i)
            af[i] = *(const f16x8*)&As[(wm + i * 16 + fm) * 32 + kq * 8];
#pragma unroll
        for (int j = 0; j < 4; ++j)
            bf[j] = *(const f16x8*)&Bs[(wn + j * 16 + fm) * 32 + kq * 8];
#pragma unroll
        for (int i = 0; i < 4; ++i)
#pragma unroll
            for (int j = 0; j < 4; ++j)
                acc[i][j] = __builtin_amdgcn_mfma_f32_16x16x32_f16(af[i], bf[j], acc[i][j], 0, 0, 0);
    }

#pragma unroll
    for (int i = 0; i < 4; ++i) {
#pragma unroll
        for (int j = 0; j < 4; ++j) {
            const int col = n0 + wn + j * 16 + fm;
            const int rowb = m0 + wm + i * 16 + kq * 4;
            float4 vv;
#pragma unroll
            for (int r = 0; r < 4; ++r) {
                const int m = rowb + r;
                float v = acc[i][j][r];
                if (bias) v += bias[col];
                if (addC) v += addC[(size_t)m * ldc + col];
                ((float*)&vv)[r] = v;
            }
            if (CT) {   // rows rowb..rowb+3 are consecutive n within one batch
                const int bb = rowb >> 12;
                *(float4*)&CT[(size_t)(bb * DP_ + col) * N_ + (rowb & (N_ - 1))] = vv;
            } else if (Cb) {
#pragma unroll
                for (int r = 0; r < 4; ++r)
                    Cb[(size_t)(rowb + r) * ldc + col] = (f16)((float*)&vv)[r];
            }
        }
    }
}

// ---------------- one-shot prep: weight transpose-casts + straight casts (f16) ----------------
// k/v rows of catW INTERLEAVED: k-col c -> row 256+8*(c/4)+(c%4); v-col c -> +4.
__global__ __launch_bounds__(256) void prep_kernel(
    const float* __restrict__ wq, const float* __restrict__ wk, const float* __restrict__ wv,
    const float* __restrict__ fd2, const float* __restrict__ fc1, const float* __restrict__ fc2,
    const float* __restrict__ feat,
    f16* __restrict__ catW, f16* __restrict__ fc2T, f16* __restrict__ bt2,
    f16* __restrict__ fd2c, f16* __restrict__ wqc, f16* __restrict__ fc1c,
    f16* __restrict__ featb)
{
    __shared__ float t[32][33];
    const int job = blockIdx.z;
    const int tid = threadIdx.x;

    if (job < 4) {
        const float* in; int R, C;
        switch (job) {
            case 0: in = wq;  R = DM_; C = DM_; break;
            case 1: in = wk;  R = DM_; C = DM_; break;
            case 2: in = wv;  R = DM_; C = DM_; break;
            default: in = fc2; R = DM_; C = DP_; break;
        }
        const int c0 = blockIdx.x * 32, r0 = blockIdx.y * 32;
        if (c0 >= C || r0 >= R) return;
        const int lx = tid & 31, ly = tid >> 5;
#pragma unroll
        for (int i = 0; i < 32; i += 8)
            t[ly + i][lx] = in[(size_t)(r0 + ly + i) * C + c0 + lx];
        __syncthreads();
#pragma unroll
        for (int i = 0; i < 32; i += 8) {
            const int c = c0 + ly + i;
            const f16 v = (f16)t[lx][ly + i];
            int n;
            switch (job) {
                case 0: n = c; break;
                case 1: n = 256 + ((c >> 2) << 3) + (c & 3); break;
                case 2: n = 256 + ((c >> 2) << 3) + 4 + (c & 3); break;
                default: n = -1; break;
            }
            if (job < 3) {
                catW[(size_t)n * DM_ + r0 + lx] = v;
            } else {
                fc2T[(size_t)c * DM_ + r0 + lx] = v;
                bt2[(size_t)c * 512 + 256 + r0 + lx] = v;
            }
        }
    } else {
        const int bid = blockIdx.y * 8 + blockIdx.x;
        const int tId = bid * 256 + tid;
        const float* in; f16* outp; int n4;
        if (job == 4)      { in = fd2;  outp = fd2c;  n4 = (DM_ * DM_) / 4; }
        else if (job == 5) { in = wq;   outp = wqc;   n4 = (DM_ * DM_) / 4; }
        else if (job == 6) { in = fc1;  outp = fc1c;  n4 = (DP_ * DM_) / 4; }
        else               { in = feat; outp = featb; n4 = (NPTS * DP_) / 4; }
        for (int i = tId; i < n4; i += 16384) {
            const float4 v = ((const float4*)in)[i];
            const u32 lo = asu32(pkrtz(v.x, v.y));
            const u32 hi = asu32(pkrtz(v.z, v.w));
            ((uint2*)outp)[i] = make_uint2(lo, hi);
        }
    }
}

// ---------------- folded bias vectors ----------------
__global__ __launch_bounds__(256) void bias_kernel(
    const float* __restrict__ fc1_b, const float* __restrict__ fd2_b,
    const float* __restrict__ fc2_w, const float* __restrict__ fc2_b,
    const f16* __restrict__ catW,
    float* __restrict__ b_all, float* __restrict__ bias2)
{
    const int tid = threadIdx.x;
    if (blockIdx.x < 4) {
        const int n = blockIdx.x * 256 + tid;
        float s = 0.0f;
        for (int j = 0; j < DM_; ++j)
            s += fc1_b[j] * (float)catW[(size_t)n * DM_ + j];
        b_all[n] = s;
    } else if (tid < DP_) {
        float s = fc2_b[tid];
        for (int t = 0; t < DM_; ++t)
            s += fd2_b[t] * fc2_w[(size_t)t * DP_ + tid];
        bias2[tid] = s;
    }
}

// ---------------- fused attention: one WAVE per point; 16 kv rows held in VGPRs ----------------
// __launch_bounds__(256,1): VGPR cap 512 (round 11's default cap 128 made the compiler
// re-sink the prefetch — VGPR stayed 80, no speedup). With the cap lifted, kvr[16]
// (64 VGPRs) stays resident and ~16 gathers are in flight per wave.
__global__ __launch_bounds__(256, 1) void attn_kernel(
    const float* __restrict__ xyz, const f16* __restrict__ qkv,
    const int* __restrict__ knn_idx,
    const float* __restrict__ fd1_w, const float* __restrict__ fd1_b,
    const float* __restrict__ fd2_b,
    f16* __restrict__ ab)
{
    const int wave = threadIdx.x >> 6, l = threadIdx.x & 63;
    const int p = blockIdx.x * 4 + wave;
    const int c0 = l * 4;

    int gi = 0; float dx = 0.0f, dy = 0.0f, dz = 0.0f;
    if (l < 16) {
        gi = knn_idx[p * K_ + l];
        dx = xyz[(size_t)p * 3 + 0] - xyz[(size_t)gi * 3 + 0];
        dy = xyz[(size_t)p * 3 + 1] - xyz[(size_t)gi * 3 + 1];
        dz = xyz[(size_t)p * 3 + 2] - xyz[(size_t)gi * 3 + 2];
    }

    // prefetch ALL 16 neighbor kv rows (independent 16B loads, stay in flight)
    uint4 kvr[16];
#pragma unroll
    for (int k = 0; k < 16; ++k) {
        const int gik = __shfl(gi, k);
        kvr[k] = *(const uint4*)(qkv + (size_t)gik * 1024 + 256 + l * 8);
    }

    const uint2 qu  = *(const uint2*)(qkv + (size_t)p * 1024 + c0);
    const uint2 qpu = *(const uint2*)(qkv + (size_t)p * 1024 + 768 + c0);
    const h2 q01 = ash2(qu.x), q23 = ash2(qu.y);
    const h2 qp01 = ash2(qpu.x), qp23 = ash2(qpu.y);

    const float4 w0 = *(const float4*)&fd1_w[c0];
    const float4 w1 = *(const float4*)&fd1_w[DM_ + c0];
    const float4 w2 = *(const float4*)&fd1_w[2 * DM_ + c0];
    const float4 b1 = *(const float4*)&fd1_b[c0];
    const float4 f2b = *(const float4*)&fd2_b[c0];
    const h2 f2b01 = pkrtz(f2b.x, f2b.y);
    const h2 f2b23 = pkrtz(f2b.z, f2b.w);

    // qb = q . fd2_b (constant over k)
    float qb;
    {
        float tq = __builtin_amdgcn_fdot2(q01, f2b01, 0.0f, false);
        tq = __builtin_amdgcn_fdot2(q23, f2b23, tq, false);
#pragma unroll
        for (int off = 1; off < 64; off <<= 1) tq += __shfl_xor(tq, off);
        qb = tq;
    }

    // phase 1: logits via f16 dot2; packed h kept in regs for phase 2
    float lg[16];
    u32 h01r[16], h23r[16];
#pragma unroll
    for (int k = 0; k < 16; ++k) {
        const float d0 = __shfl(dx, k), d1 = __shfl(dy, k), d2 = __shfl(dz, k);
        const float h0 = fmaxf(d0 * w0.x + d1 * w1.x + d2 * w2.x + b1.x, 0.0f);
        const float h1 = fmaxf(d0 * w0.y + d1 * w1.y + d2 * w2.y + b1.y, 0.0f);
        const float h2v = fmaxf(d0 * w0.z + d1 * w1.z + d2 * w2.z + b1.z, 0.0f);
        const float h3 = fmaxf(d0 * w0.w + d1 * w1.w + d2 * w2.w + b1.w, 0.0f);
        const h2 hp01 = pkrtz(h0, h1);
        const h2 hp23 = pkrtz(h2v, h3);
        h01r[k] = asu32(hp01); h23r[k] = asu32(hp23);
        float t = __builtin_amdgcn_fdot2(ash2(kvr[k].x), q01, 0.0f, false);
        t = __builtin_amdgcn_fdot2(ash2(kvr[k].y), q23, t, false);
        t = __builtin_amdgcn_fdot2(hp01, qp01, t, false);
        t = __builtin_amdgcn_fdot2(hp23, qp23, t, false);
#pragma unroll
        for (int off = 1; off < 64; off <<= 1) t += __shfl_xor(t, off);
        lg[k] = t;
    }

    // softmax over 16 (redundant per lane, all registers)
    float att[16];
    {
        float mx = -3.0e38f;
#pragma unroll
        for (int k = 0; k < 16; ++k) {
            att[k] = (lg[k] + qb) * (1.0f / 16.0f);
            mx = fmaxf(mx, att[k]);
        }
        float s = 0.0f;
#pragma unroll
        for (int k = 0; k < 16; ++k) { att[k] = __expf(att[k] - mx); s += att[k]; }
        const float inv = 1.0f / s;
#pragma unroll
        for (int k = 0; k < 16; ++k) att[k] *= inv;
    }

    // phase 2: pure VALU — rbar = sum att*v (kvr regs), hbar = sum att*h (regs)
    float rb[4] = {0, 0, 0, 0}, hb[4] = {0, 0, 0, 0};
#pragma unroll
    for (int k = 0; k < 16; ++k) {
        const h2 v01 = ash2(kvr[k].z), v23 = ash2(kvr[k].w);
        const h2 hh01 = ash2(h01r[k]), hh23 = ash2(h23r[k]);
        const float a = att[k];
        rb[0] = fmaf(a, (float)v01.x, rb[0]);
        rb[1] = fmaf(a, (float)v01.y, rb[1]);
        rb[2] = fmaf(a, (float)v23.x, rb[2]);
        rb[3] = fmaf(a, (float)v23.y, rb[3]);
        hb[0] = fmaf(a, (float)hh01.x, hb[0]);
        hb[1] = fmaf(a, (float)hh01.y, hb[1]);
        hb[2] = fmaf(a, (float)hh23.x, hb[2]);
        hb[3] = fmaf(a, (float)hh23.y, hb[3]);
    }

    const uint2 ho = make_uint2(asu32(pkrtz(hb[0], hb[1])), asu32(pkrtz(hb[2], hb[3])));
    const uint2 ro = make_uint2(asu32(pkrtz(rb[0], rb[1])), asu32(pkrtz(rb[2], rb[3])));
    *(uint2*)(ab + (size_t)p * 512 + c0) = ho;
    *(uint2*)(ab + (size_t)p * 512 + 256 + c0) = ro;
}

extern "C" void kernel_launch(void* const* d_in, const int* in_sizes, int n_in,
                              void* d_out, int out_size, void* d_ws, size_t ws_size,
                              hipStream_t stream)
{
    const float* features = (const float*)d_in[0];
    const float* xyz   = (const float*)d_in[1];
    const float* fc1_w = (const float*)d_in[2];
    const float* fc1_b = (const float*)d_in[3];
    const float* fc2_w = (const float*)d_in[4];
    const float* fc2_b = (const float*)d_in[5];
    const float* fd1_w = (const float*)d_in[6];
    const float* fd1_b = (const float*)d_in[7];
    const float* fd2_w = (const float*)d_in[8];
    const float* fd2_b = (const float*)d_in[9];
    const float* wq    = (const float*)d_in[10];
    const float* wk    = (const float*)d_in[11];
    const float* wv    = (const float*)d_in[12];
    float* out = (float*)d_out;

    char* base = (char*)d_ws;
    const size_t MB = 1024 * 1024;
    u32*  part = (u32*)(base + 0);                 // 16 MB (16 segs), dead after mergeA
    f16*  ab   = (f16*)(base + 0);                 // 16 MB [hbar|rbar]
    u32*  m4   = (u32*)(base + 16 * MB);           // 4 MB (4 lists), dead after mergeB
    f16*  qkv  = (f16*)(base + 36 * MB);           // 32 MB
    f16*  featb = (f16*)(base + 68 * MB);          // 4 MB
    int*  idx  = (int*)(base + 72 * MB);           // 1 MB
    char* wb = base + 73 * MB;
    f16* catW  = (f16*)(wb + 0);                   // [1024][256] = 512 KB
    f16* WallT = (f16*)(wb + 512 * 1024);          // [1024][128] = 256 KB
    f16* bt2   = (f16*)(wb + 768 * 1024);          // [128][512]  = 128 KB
    f16* fd2c  = (f16*)(wb + 896 * 1024);
    f16* wqc   = (f16*)(wb + 1024 * 1024);
    f16* fc1c  = (f16*)(wb + 1152 * 1024);
    f16* fc2T  = (f16*)(wb + 1216 * 1024);
    float* b_all = (float*)(wb + 1280 * 1024);
    float* bias2 = (float*)(wb + 1284 * 1024);

    const dim3 blk(256);

    // casts (also seeds bt2 cols [256,512) with fc2^T); k/v rows interleaved in catW
    prep_kernel<<<dim3(8, 8, 8), blk, 0, stream>>>(wq, wk, wv, fd2_w, fc1_w, fc2_w, features,
                                                   catW, fc2T, bt2, fd2c, wqc, fc1c, featb);
    // catW rows 768..1023: Wqp^T[a][b] = sum_j fd2[a][j]*wq[b][j]
    gemm_f16_kernel<<<dim3(2, 2), blk, 0, stream>>>(
        fd2c, wqc, nullptr, nullptr, nullptr, catW + 768 * 256, DM_, DM_, DM_, DM_);
    // folded biases
    bias_kernel<<<dim3(5), blk, 0, stream>>>(fc1_b, fd2_b, fc2_w, fc2_b, catW, b_all, bias2);
    // WallT[n][k] = sum_j catW[n][j]*fc1_w[k][j]
    gemm_f16_kernel<<<dim3(1, 8), blk, 0, stream>>>(
        catW, fc1c, nullptr, nullptr, nullptr, WallT, 1024, DP_, DM_, DP_);
    // bt2 cols [0,256): Wof^T[n][j] = sum_t fc2[t][n]*fd2[j][t]
    gemm_f16_kernel<<<dim3(2, 1), blk, 0, stream>>>(
        fc2T, fd2c, nullptr, nullptr, nullptr, bt2, DP_, DM_, DM_, 512);

    // KNN: 16 segments, two-stage merge (A: 1024 waves, B: 256 waves)
    knn_part_kernel<<<dim3(N_ / 256, SEG_, B_), blk, 0, stream>>>(xyz, part);
    knn_mergeA_kernel<<<dim3(NPTS / 256, 4), blk, 0, stream>>>(part, m4);
    knn_mergeB_kernel<<<dim3(NPTS / 256), blk, 0, stream>>>(m4, idx);

    // [q | kv-interleaved | qp] = features @ WallT^T + b_all
    gemm_f16_kernel<<<dim3(1024 / 128, NPTS / 128), blk, 0, stream>>>(
        featb, WallT, b_all, nullptr, nullptr, qkv, NPTS, 1024, DP_, 1024);

    // fused attention -> ab = [hbar | rbar]
    attn_kernel<<<dim3(NPTS / 4), blk, 0, stream>>>(xyz, qkv, idx, fd1_w, fd1_b, fd2_b, ab);

    // out = ab @ bt2^T + bias2 + features, stored TRANSPOSED directly to d_out
    gemm_f16_kernel<<<dim3(1, NPTS / 128), blk, 0, stream>>>(
        ab, bt2, bias2, features, out, nullptr, NPTS, DP_, 512, DP_);

    (void)in_sizes; (void)n_in; (void)out_size; (void)ws_size;
}

// Round 13
// 283.815 us; speedup vs baseline: 1.0208x; 1.0187x over previous
//
#include <hip/hip_runtime.h>
#include <hip/hip_bf16.h>
#include <math.h>

#define B_   4
#define N_   4096
#define K_   16
#define DP_  128
#define DM_  256
#define NPTS (B_ * N_)
#define SEG_ 16
#define CAND_ (N_ / SEG_)   // 256 candidates per segment

typedef unsigned int u32;
typedef unsigned char u8;
typedef _Float16 f16;
typedef __attribute__((ext_vector_type(2))) __fp16 h2;     // matches cvt_pkrtz ABI
typedef __attribute__((ext_vector_type(8))) _Float16 f16x8; // MFMA operand
typedef __attribute__((ext_vector_type(4))) float floatx4;

static __device__ __forceinline__ h2 pkrtz(float a, float b) {
    return __builtin_amdgcn_cvt_pkrtz(a, b);
}
static __device__ __forceinline__ u32 asu32(h2 h) { return __builtin_bit_cast(u32, h); }
static __device__ __forceinline__ h2 ash2(u32 u) { return __builtin_bit_cast(h2, u); }

// ---- bitonic primitives on u32 registers ----
#define CEXA(x, y) { u32 _lo = min(x, y); y = max(x, y); x = _lo; }   // x<=y
#define CEXD(x, y) { u32 _hi = max(x, y); y = min(x, y); x = _hi; }   // x>=y

// full bitonic sort of 16, DESCENDING; 80 CEX
static __device__ __forceinline__ void sort16_desc(u32 c[16]) {
    CEXD(c[0],c[1]);  CEXA(c[2],c[3]);  CEXD(c[4],c[5]);  CEXA(c[6],c[7]);
    CEXD(c[8],c[9]);  CEXA(c[10],c[11]); CEXD(c[12],c[13]); CEXA(c[14],c[15]);

    CEXD(c[0],c[2]);  CEXD(c[1],c[3]);  CEXA(c[4],c[6]);  CEXA(c[5],c[7]);
    CEXD(c[8],c[10]); CEXD(c[9],c[11]); CEXA(c[12],c[14]); CEXA(c[13],c[15]);
    CEXD(c[0],c[1]);  CEXD(c[2],c[3]);  CEXA(c[4],c[5]);  CEXA(c[6],c[7]);
    CEXD(c[8],c[9]);  CEXD(c[10],c[11]); CEXA(c[12],c[13]); CEXA(c[14],c[15]);

    CEXD(c[0],c[4]);  CEXD(c[1],c[5]);  CEXD(c[2],c[6]);  CEXD(c[3],c[7]);
    CEXA(c[8],c[12]); CEXA(c[9],c[13]); CEXA(c[10],c[14]); CEXA(c[11],c[15]);
    CEXD(c[0],c[2]);  CEXD(c[1],c[3]);  CEXD(c[4],c[6]);  CEXD(c[5],c[7]);
    CEXA(c[8],c[10]); CEXA(c[9],c[11]); CEXA(c[12],c[14]); CEXA(c[13],c[15]);
    CEXD(c[0],c[1]);  CEXD(c[2],c[3]);  CEXD(c[4],c[5]);  CEXD(c[6],c[7]);
    CEXA(c[8],c[9]);  CEXA(c[10],c[11]); CEXA(c[12],c[13]); CEXA(c[14],c[15]);

    CEXD(c[0],c[8]);  CEXD(c[1],c[9]);  CEXD(c[2],c[10]); CEXD(c[3],c[11]);
    CEXD(c[4],c[12]); CEXD(c[5],c[13]); CEXD(c[6],c[14]); CEXD(c[7],c[15]);
    CEXD(c[0],c[4]);  CEXD(c[1],c[5]);  CEXD(c[2],c[6]);  CEXD(c[3],c[7]);
    CEXD(c[8],c[12]); CEXD(c[9],c[13]); CEXD(c[10],c[14]); CEXD(c[11],c[15]);
    CEXD(c[0],c[2]);  CEXD(c[1],c[3]);  CEXD(c[4],c[6]);  CEXD(c[5],c[7]);
    CEXD(c[8],c[10]); CEXD(c[9],c[11]); CEXD(c[12],c[14]); CEXD(c[13],c[15]);
    CEXD(c[0],c[1]);  CEXD(c[2],c[3]);  CEXD(c[4],c[5]);  CEXD(c[6],c[7]);
    CEXD(c[8],c[9]);  CEXD(c[10],c[11]); CEXD(c[12],c[13]); CEXD(c[14],c[15]);
}

// L is bitonic -> sort ascending; 32 CEX
static __device__ __forceinline__ void remerge16_asc(u32 L[16]) {
    CEXA(L[0],L[8]);  CEXA(L[1],L[9]);  CEXA(L[2],L[10]); CEXA(L[3],L[11]);
    CEXA(L[4],L[12]); CEXA(L[5],L[13]); CEXA(L[6],L[14]); CEXA(L[7],L[15]);
    CEXA(L[0],L[4]);  CEXA(L[1],L[5]);  CEXA(L[2],L[6]);  CEXA(L[3],L[7]);
    CEXA(L[8],L[12]); CEXA(L[9],L[13]); CEXA(L[10],L[14]); CEXA(L[11],L[15]);
    CEXA(L[0],L[2]);  CEXA(L[1],L[3]);  CEXA(L[4],L[6]);  CEXA(L[5],L[7]);
    CEXA(L[8],L[10]); CEXA(L[9],L[11]); CEXA(L[12],L[14]); CEXA(L[13],L[15]);
    CEXA(L[0],L[1]);  CEXA(L[2],L[3]);  CEXA(L[4],L[5]);  CEXA(L[6],L[7]);
    CEXA(L[8],L[9]);  CEXA(L[10],L[11]); CEXA(L[12],L[13]); CEXA(L[14],L[15]);
}

// ---------------- KNN phase 1: bitonic-batch top-16 per (point, segment) ----------------
// Rank key: e = 0.5*|c|^2 - dot(x_n, c)  — per-thread ordering identical to d2.
__global__ __launch_bounds__(256, 1) void knn_part_kernel(const float* __restrict__ xyz,
                                                          u32* __restrict__ part)
{
    const int b = blockIdx.z;
    const int s = blockIdx.y;
    const int n = blockIdx.x * 256 + threadIdx.x;
    const float* xb = xyz + (size_t)b * N_ * 3;
    const float xn0 = xb[n * 3 + 0], xn1 = xb[n * 3 + 1], xn2 = xb[n * 3 + 2];

    __shared__ float4 sc[CAND_];
    {
        const int m = s * CAND_ + threadIdx.x;   // CAND_ == 256 == blockDim.x
        const float a0 = xb[m * 3 + 0];
        const float a1 = xb[m * 3 + 1];
        const float a2 = xb[m * 3 + 2];
        sc[threadIdx.x] = make_float4(a0, a1, a2, 0.5f * (a0 * a0 + a1 * a1 + a2 * a2));
    }
    __syncthreads();

    u32 L[16];
#pragma unroll
    for (int i = 0; i < 16; ++i) L[i] = 0xFFFFFFFFu;

    const u32 ibase = (u32)(s * CAND_);
    for (int m0 = 0; m0 < CAND_; m0 += 16) {
        u32 c[16];
#pragma unroll
        for (int t = 0; t < 16; ++t) {
            const float4 cc = sc[m0 + t];
            const float dot = xn0 * cc.x + xn1 * cc.y + xn2 * cc.z;
            const float e = cc.w - dot;
            const int ib = __float_as_int(e);
            const u32 tk = (u32)ib ^ (u32)((ib >> 31) | 0x80000000);
            c[t] = (tk & 0xFFFFF000u) | (ibase + (u32)(m0 + t));
        }
        sort16_desc(c);
#pragma unroll
        for (int i = 0; i < 16; ++i) L[i] = min(L[i], c[i]);
        remerge16_asc(L);
    }

    const int p = b * N_ + n;
#pragma unroll
    for (int j = 0; j < 16; ++j)
        part[(size_t)(s * 16 + j) * NPTS + p] = L[j];
}

// ---------------- KNN merge stage A: 4 segments -> 1 sorted list (x4 groups) ----------------
__global__ __launch_bounds__(256, 1) void knn_mergeA_kernel(const u32* __restrict__ part,
                                                            u32* __restrict__ m4)
{
    const int g = blockIdx.y;                                // group 0..3
    const int p = blockIdx.x * 256 + threadIdx.x;            // global point id

    u32 L[16];
#pragma unroll
    for (int i = 0; i < 16; ++i) L[i] = 0xFFFFFFFFu;

    for (int s = g * 4; s < g * 4 + 4; ++s) {
        u32 seg[16];
#pragma unroll
        for (int j = 0; j < 16; ++j)
            seg[j] = part[(size_t)(s * 16 + j) * NPTS + p];
#pragma unroll
        for (int i = 0; i < 16; ++i) L[i] = min(L[i], seg[15 - i]);
        remerge16_asc(L);
    }
#pragma unroll
    for (int j = 0; j < 16; ++j)
        m4[(size_t)(g * 16 + j) * NPTS + p] = L[j];
}

// ---------------- KNN merge stage B: 4 sorted lists -> final top-16 indices ----------------
__global__ __launch_bounds__(256, 1) void knn_mergeB_kernel(const u32* __restrict__ m4,
                                                            int* __restrict__ knn_idx)
{
    const int p = blockIdx.x * 256 + threadIdx.x;
    const int b = p >> 12;

    u32 L[16];
#pragma unroll
    for (int i = 0; i < 16; ++i) L[i] = 0xFFFFFFFFu;

    for (int g = 0; g < 4; ++g) {
        u32 seg[16];
#pragma unroll
        for (int j = 0; j < 16; ++j)
            seg[j] = m4[(size_t)(g * 16 + j) * NPTS + p];
#pragma unroll
        for (int i = 0; i < 16; ++i) L[i] = min(L[i], seg[15 - i]);
        remerge16_asc(L);
    }

    int* o = knn_idx + (size_t)p * K_;
#pragma unroll
    for (int i = 0; i < 16; ++i) o[i] = b * N_ + (int)(L[i] & 0xFFFu);
}

// ---------------- f16 MFMA GEMM: C[M,N] = A[M,K] @ Bt[N,K]^T (+bias +addC) ----------------
// CT != null: store TRANSPOSED to [B][DP][N] fp32 (fused output transpose).
__global__ __launch_bounds__(256) void gemm_f16_kernel(
    const f16* __restrict__ A,     // [M][K]
    const f16* __restrict__ Bt,    // [N][K]
    const float* __restrict__ bias,
    const float* __restrict__ addC,   // fp32, row stride ldc
    float* __restrict__ CT,        // transposed fp32 out [B][DP][N], or null
    f16* __restrict__ Cb,          // f16 out, row stride ldc, or null
    int M, int N, int K, int ldc)
{
    __shared__ __align__(16) f16 As[128 * 32];
    __shared__ __align__(16) f16 Bs[128 * 32];
    const int tid = threadIdx.x;
    const int m0 = blockIdx.y * 128, n0 = blockIdx.x * 128;
    const int w = tid >> 6, l = tid & 63;
    const int wm = (w >> 1) * 64, wn = (w & 1) * 64;
    const int fm = l & 15, kq = l >> 4;

    floatx4 acc[4][4];
#pragma unroll
    for (int i = 0; i < 4; ++i)
#pragma unroll
        for (int j = 0; j < 4; ++j)
            acc[i][j] = (floatx4){0.0f, 0.0f, 0.0f, 0.0f};

    for (int k0 = 0; k0 < K; k0 += 32) {
        __syncthreads();
#pragma unroll
        for (int c = 0; c < 2; ++c) {
            const int li = tid + c * 256;
            const int row = li >> 2, part = li & 3;
            *(uint4*)&As[row * 32 + part * 8] =
                *(const uint4*)&A[(size_t)(m0 + row) * K + k0 + part * 8];
            *(uint4*)&Bs[row * 32 + part * 8] =
                *(const uint4*)&Bt[(size_t)(n0 + row) * K + k0 + part * 8];
        }
        __syncthreads();
        f16x8 af[4], bf[4];
#pragma unroll
        for (int i = 0; i < 4; ++i)
            af[i] = *(const f16x8*)&As[(wm + i * 16 + fm) * 32 + kq * 8];
#pragma unroll
        for (int j = 0; j < 4; ++j)
            bf[j] = *(const f16x8*)&Bs[(wn + j * 16 + fm) * 32 + kq * 8];
#pragma unroll
        for (int i = 0; i < 4; ++i)
#pragma unroll
            for (int j = 0; j < 4; ++j)
                acc[i][j] = __builtin_amdgcn_mfma_f32_16x16x32_f16(af[i], bf[j], acc[i][j], 0, 0, 0);
    }

#pragma unroll
    for (int i = 0; i < 4; ++i) {
#pragma unroll
        for (int j = 0; j < 4; ++j) {
            const int col = n0 + wn + j * 16 + fm;
            const int rowb = m0 + wm + i * 16 + kq * 4;
            float4 vv;
#pragma unroll
            for (int r = 0; r < 4; ++r) {
                const int m = rowb + r;
                float v = acc[i][j][r];
                if (bias) v += bias[col];
                if (addC) v += addC[(size_t)m * ldc + col];
                ((float*)&vv)[r] = v;
            }
            if (CT) {   // rows rowb..rowb+3 are consecutive n within one batch
                const int bb = rowb >> 12;
                *(float4*)&CT[(size_t)(bb * DP_ + col) * N_ + (rowb & (N_ - 1))] = vv;
            } else if (Cb) {
#pragma unroll
                for (int r = 0; r < 4; ++r)
                    Cb[(size_t)(rowb + r) * ldc + col] = (f16)((float*)&vv)[r];
            }
        }
    }
}

// ---------------- kv8: convert the kv region of qkv to fp8 e4m3 gather buffer ----------------
// kv8 row p = 512 B: group g (dim 4g..4g+3) at offset 8g: bytes 0-3 = k fp8, 4-7 = v fp8.
__global__ __launch_bounds__(256) void kv8_kernel(const f16* __restrict__ qkv,
                                                  u8* __restrict__ kv8)
{
    const int t = blockIdx.x * 256 + threadIdx.x;   // 0 .. NPTS*64-1
    const int p = t >> 6, g = t & 63;
    const uint4 kv = *(const uint4*)(qkv + (size_t)p * 1024 + 256 + g * 8);
    const h2 k01 = ash2(kv.x), k23 = ash2(kv.y), v01 = ash2(kv.z), v23 = ash2(kv.w);
    int lo = 0, hi = 0;
    lo = __builtin_amdgcn_cvt_pk_fp8_f32((float)k01.x, (float)k01.y, lo, false);
    lo = __builtin_amdgcn_cvt_pk_fp8_f32((float)k23.x, (float)k23.y, lo, true);
    hi = __builtin_amdgcn_cvt_pk_fp8_f32((float)v01.x, (float)v01.y, hi, false);
    hi = __builtin_amdgcn_cvt_pk_fp8_f32((float)v23.x, (float)v23.y, hi, true);
    *(uint2*)(kv8 + (size_t)p * 512 + g * 8) = make_uint2((u32)lo, (u32)hi);
}

// ---------------- one-shot prep: weight transpose-casts + straight casts (f16) ----------------
// k/v rows of catW INTERLEAVED: k-col c -> row 256+8*(c/4)+(c%4); v-col c -> +4.
__global__ __launch_bounds__(256) void prep_kernel(
    const float* __restrict__ wq, const float* __restrict__ wk, const float* __restrict__ wv,
    const float* __restrict__ fd2, const float* __restrict__ fc1, const float* __restrict__ fc2,
    const float* __restrict__ feat,
    f16* __restrict__ catW, f16* __restrict__ fc2T, f16* __restrict__ bt2,
    f16* __restrict__ fd2c, f16* __restrict__ wqc, f16* __restrict__ fc1c,
    f16* __restrict__ featb)
{
    __shared__ float t[32][33];
    const int job = blockIdx.z;
    const int tid = threadIdx.x;

    if (job < 4) {
        const float* in; int R, C;
        switch (job) {
            case 0: in = wq;  R = DM_; C = DM_; break;
            case 1: in = wk;  R = DM_; C = DM_; break;
            case 2: in = wv;  R = DM_; C = DM_; break;
            default: in = fc2; R = DM_; C = DP_; break;
        }
        const int c0 = blockIdx.x * 32, r0 = blockIdx.y * 32;
        if (c0 >= C || r0 >= R) return;
        const int lx = tid & 31, ly = tid >> 5;
#pragma unroll
        for (int i = 0; i < 32; i += 8)
            t[ly + i][lx] = in[(size_t)(r0 + ly + i) * C + c0 + lx];
        __syncthreads();
#pragma unroll
        for (int i = 0; i < 32; i += 8) {
            const int c = c0 + ly + i;
            const f16 v = (f16)t[lx][ly + i];
            int n;
            switch (job) {
                case 0: n = c; break;
                case 1: n = 256 + ((c >> 2) << 3) + (c & 3); break;
                case 2: n = 256 + ((c >> 2) << 3) + 4 + (c & 3); break;
                default: n = -1; break;
            }
            if (job < 3) {
                catW[(size_t)n * DM_ + r0 + lx] = v;
            } else {
                fc2T[(size_t)c * DM_ + r0 + lx] = v;
                bt2[(size_t)c * 512 + 256 + r0 + lx] = v;
            }
        }
    } else {
        const int bid = blockIdx.y * 8 + blockIdx.x;
        const int tId = bid * 256 + tid;
        const float* in; f16* outp; int n4;
        if (job == 4)      { in = fd2;  outp = fd2c;  n4 = (DM_ * DM_) / 4; }
        else if (job == 5) { in = wq;   outp = wqc;   n4 = (DM_ * DM_) / 4; }
        else if (job == 6) { in = fc1;  outp = fc1c;  n4 = (DP_ * DM_) / 4; }
        else               { in = feat; outp = featb; n4 = (NPTS * DP_) / 4; }
        for (int i = tId; i < n4; i += 16384) {
            const float4 v = ((const float4*)in)[i];
            const u32 lo = asu32(pkrtz(v.x, v.y));
            const u32 hi = asu32(pkrtz(v.z, v.w));
            ((uint2*)outp)[i] = make_uint2(lo, hi);
        }
    }
}

// ---------------- folded bias vectors ----------------
__global__ __launch_bounds__(256) void bias_kernel(
    const float* __restrict__ fc1_b, const float* __restrict__ fd2_b,
    const float* __restrict__ fc2_w, const float* __restrict__ fc2_b,
    const f16* __restrict__ catW,
    float* __restrict__ b_all, float* __restrict__ bias2)
{
    const int tid = threadIdx.x;
    if (blockIdx.x < 4) {
        const int n = blockIdx.x * 256 + tid;
        float s = 0.0f;
        for (int j = 0; j < DM_; ++j)
            s += fc1_b[j] * (float)catW[(size_t)n * DM_ + j];
        b_all[n] = s;
    } else if (tid < DP_) {
        float s = fc2_b[tid];
        for (int t = 0; t < DM_; ++t)
            s += fd2_b[t] * fc2_w[(size_t)t * DP_ + tid];
        bias2[tid] = s;
    }
}

// ---------------- fused attention: one WAVE per point; fp8 kv gather (8 B/lane/neighbor) ----
// kv8 row (512 B): lane l reads uint2 at offset 8l = {k fp8 x4, v fp8 x4} for dims 4l..4l+3.
// All 16 gathers issued before an asm memory barrier (pins them; 32 VGPRs of payload).
__global__ __launch_bounds__(256, 1) void attn_kernel(
    const float* __restrict__ xyz, const f16* __restrict__ qkv,
    const u8* __restrict__ kv8, const int* __restrict__ knn_idx,
    const float* __restrict__ fd1_w, const float* __restrict__ fd1_b,
    const float* __restrict__ fd2_b,
    f16* __restrict__ ab)
{
    const int wave = threadIdx.x >> 6, l = threadIdx.x & 63;
    const int p = blockIdx.x * 4 + wave;
    const int c0 = l * 4;

    int gi = 0; float dx = 0.0f, dy = 0.0f, dz = 0.0f;
    if (l < 16) {
        gi = knn_idx[p * K_ + l];
        dx = xyz[(size_t)p * 3 + 0] - xyz[(size_t)gi * 3 + 0];
        dy = xyz[(size_t)p * 3 + 1] - xyz[(size_t)gi * 3 + 1];
        dz = xyz[(size_t)p * 3 + 2] - xyz[(size_t)gi * 3 + 2];
    }

    // prefetch ALL 16 neighbor kv8 rows (independent 8B loads), pin above compute
    uint2 kvr8[16];
#pragma unroll
    for (int k = 0; k < 16; ++k) {
        const int gik = __shfl(gi, k);
        kvr8[k] = *(const uint2*)(kv8 + (size_t)gik * 512 + l * 8);
    }
    asm volatile("" ::: "memory");   // loads may not sink past this

    const uint2 qu  = *(const uint2*)(qkv + (size_t)p * 1024 + c0);
    const uint2 qpu = *(const uint2*)(qkv + (size_t)p * 1024 + 768 + c0);
    const h2 qh01 = ash2(qu.x), qh23 = ash2(qu.y);
    const h2 qph01 = ash2(qpu.x), qph23 = ash2(qpu.y);
    const float q0 = (float)qh01.x, q1 = (float)qh01.y, q2 = (float)qh23.x, q3 = (float)qh23.y;
    const float qp0 = (float)qph01.x, qp1 = (float)qph01.y, qp2 = (float)qph23.x, qp3 = (float)qph23.y;

    const float4 w0 = *(const float4*)&fd1_w[c0];
    const float4 w1 = *(const float4*)&fd1_w[DM_ + c0];
    const float4 w2 = *(const float4*)&fd1_w[2 * DM_ + c0];
    const float4 b1 = *(const float4*)&fd1_b[c0];
    const float4 f2b = *(const float4*)&fd2_b[c0];

    // qb = q . fd2_b (constant over k)
    float qb;
    {
        float tq = q0 * f2b.x + q1 * f2b.y + q2 * f2b.z + q3 * f2b.w;
#pragma unroll
        for (int off = 1; off < 64; off <<= 1) tq += __shfl_xor(tq, off);
        qb = tq;
    }

    // phase 1: logits; h packed to f16 and kept for phase 2
    float lg[16];
    u32 h01r[16], h23r[16];
#pragma unroll
    for (int k = 0; k < 16; ++k) {
        const float d0 = __shfl(dx, k), d1 = __shfl(dy, k), d2 = __shfl(dz, k);
        const float h0 = fmaxf(d0 * w0.x + d1 * w1.x + d2 * w2.x + b1.x, 0.0f);
        const float h1 = fmaxf(d0 * w0.y + d1 * w1.y + d2 * w2.y + b1.y, 0.0f);
        const float h2v = fmaxf(d0 * w0.z + d1 * w1.z + d2 * w2.z + b1.z, 0.0f);
        const float h3 = fmaxf(d0 * w0.w + d1 * w1.w + d2 * w2.w + b1.w, 0.0f);
        h01r[k] = asu32(pkrtz(h0, h1));
        h23r[k] = asu32(pkrtz(h2v, h3));
        const auto k01 = __builtin_amdgcn_cvt_pk_f32_fp8((int)kvr8[k].x, false);
        const auto k23 = __builtin_amdgcn_cvt_pk_f32_fp8((int)kvr8[k].x, true);
        float t = q0 * k01[0] + q1 * k01[1] + q2 * k23[0] + q3 * k23[1]
                + h0 * qp0 + h1 * qp1 + h2v * qp2 + h3 * qp3;
#pragma unroll
        for (int off = 1; off < 64; off <<= 1) t += __shfl_xor(t, off);
        lg[k] = t;
    }

    // softmax over 16 (redundant per lane, all registers)
    float att[16];
    {
        float mx = -3.0e38f;
#pragma unroll
        for (int k = 0; k < 16; ++k) {
            att[k] = (lg[k] + qb) * (1.0f / 16.0f);
            mx = fmaxf(mx, att[k]);
        }
        float s = 0.0f;
#pragma unroll
        for (int k = 0; k < 16; ++k) { att[k] = __expf(att[k] - mx); s += att[k]; }
        const float inv = 1.0f / s;
#pragma unroll
        for (int k = 0; k < 16; ++k) att[k] *= inv;
    }

    // phase 2: pure VALU — rbar = sum att*v (kvr8 regs), hbar = sum att*h (regs)
    float rb[4] = {0, 0, 0, 0}, hb[4] = {0, 0, 0, 0};
#pragma unroll
    for (int k = 0; k < 16; ++k) {
        const auto v01 = __builtin_amdgcn_cvt_pk_f32_fp8((int)kvr8[k].y, false);
        const auto v23 = __builtin_amdgcn_cvt_pk_f32_fp8((int)kvr8[k].y, true);
        const h2 hh01 = ash2(h01r[k]), hh23 = ash2(h23r[k]);
        const float a = att[k];
        rb[0] = fmaf(a, v01[0], rb[0]);
        rb[1] = fmaf(a, v01[1], rb[1]);
        rb[2] = fmaf(a, v23[0], rb[2]);
        rb[3] = fmaf(a, v23[1], rb[3]);
        hb[0] = fmaf(a, (float)hh01.x, hb[0]);
        hb[1] = fmaf(a, (float)hh01.y, hb[1]);
        hb[2] = fmaf(a, (float)hh23.x, hb[2]);
        hb[3] = fmaf(a, (float)hh23.y, hb[3]);
    }

    const uint2 ho = make_uint2(asu32(pkrtz(hb[0], hb[1])), asu32(pkrtz(hb[2], hb[3])));
    const uint2 ro = make_uint2(asu32(pkrtz(rb[0], rb[1])), asu32(pkrtz(rb[2], rb[3])));
    *(uint2*)(ab + (size_t)p * 512 + c0) = ho;
    *(uint2*)(ab + (size_t)p * 512 + 256 + c0) = ro;
}

extern "C" void kernel_launch(void* const* d_in, const int* in_sizes, int n_in,
                              void* d_out, int out_size, void* d_ws, size_t ws_size,
                              hipStream_t stream)
{
    const float* features = (const float*)d_in[0];
    const float* xyz   = (const float*)d_in[1];
    const float* fc1_w = (const float*)d_in[2];
    const float* fc1_b = (const float*)d_in[3];
    const float* fc2_w = (const float*)d_in[4];
    const float* fc2_b = (const float*)d_in[5];
    const float* fd1_w = (const float*)d_in[6];
    const float* fd1_b = (const float*)d_in[7];
    const float* fd2_w = (const float*)d_in[8];
    const float* fd2_b = (const float*)d_in[9];
    const float* wq    = (const float*)d_in[10];
    const float* wk    = (const float*)d_in[11];
    const float* wv    = (const float*)d_in[12];
    float* out = (float*)d_out;

    char* base = (char*)d_ws;
    const size_t MB = 1024 * 1024;
    u32*  part = (u32*)(base + 0);                 // 16 MB (16 segs), dead after mergeA
    f16*  ab   = (f16*)(base + 0);                 // 16 MB [hbar|rbar]
    u32*  m4   = (u32*)(base + 16 * MB);           // 4 MB (4 lists), dead after mergeB
    u8*   kv8  = (u8*)(base + 20 * MB);            // 8 MB fp8 gather buffer
    f16*  qkv  = (f16*)(base + 36 * MB);           // 32 MB
    f16*  featb = (f16*)(base + 68 * MB);          // 4 MB
    int*  idx  = (int*)(base + 72 * MB);           // 1 MB
    char* wb = base + 73 * MB;
    f16* catW  = (f16*)(wb + 0);                   // [1024][256] = 512 KB
    f16* WallT = (f16*)(wb + 512 * 1024);          // [1024][128] = 256 KB
    f16* bt2   = (f16*)(wb + 768 * 1024);          // [128][512]  = 128 KB
    f16* fd2c  = (f16*)(wb + 896 * 1024);
    f16* wqc   = (f16*)(wb + 1024 * 1024);
    f16* fc1c  = (f16*)(wb + 1152 * 1024);
    f16* fc2T  = (f16*)(wb + 1216 * 1024);
    float* b_all = (float*)(wb + 1280 * 1024);
    float* bias2 = (float*)(wb + 1284 * 1024);

    const dim3 blk(256);

    // casts (also seeds bt2 cols [256,512) with fc2^T); k/v rows interleaved in catW
    prep_kernel<<<dim3(8, 8, 8), blk, 0, stream>>>(wq, wk, wv, fd2_w, fc1_w, fc2_w, features,
                                                   catW, fc2T, bt2, fd2c, wqc, fc1c, featb);
    // catW rows 768..1023: Wqp^T[a][b] = sum_j fd2[a][j]*wq[b][j]
    gemm_f16_kernel<<<dim3(2, 2), blk, 0, stream>>>(
        fd2c, wqc, nullptr, nullptr, nullptr, catW + 768 * 256, DM_, DM_, DM_, DM_);
    // folded biases
    bias_kernel<<<dim3(5), blk, 0, stream>>>(fc1_b, fd2_b, fc2_w, fc2_b, catW, b_all, bias2);
    // WallT[n][k] = sum_j catW[n][j]*fc1_w[k][j]
    gemm_f16_kernel<<<dim3(1, 8), blk, 0, stream>>>(
        catW, fc1c, nullptr, nullptr, nullptr, WallT, 1024, DP_, DM_, DP_);
    // bt2 cols [0,256): Wof^T[n][j] = sum_t fc2[t][n]*fd2[j][t]
    gemm_f16_kernel<<<dim3(2, 1), blk, 0, stream>>>(
        fc2T, fd2c, nullptr, nullptr, nullptr, bt2, DP_, DM_, DM_, 512);

    // KNN: 16 segments, two-stage merge (A: 1024 waves, B: 256 waves)
    knn_part_kernel<<<dim3(N_ / 256, SEG_, B_), blk, 0, stream>>>(xyz, part);
    knn_mergeA_kernel<<<dim3(NPTS / 256, 4), blk, 0, stream>>>(part, m4);
    knn_mergeB_kernel<<<dim3(NPTS / 256), blk, 0, stream>>>(m4, idx);

    // [q | kv-interleaved | qp] = features @ WallT^T + b_all
    gemm_f16_kernel<<<dim3(1024 / 128, NPTS / 128), blk, 0, stream>>>(
        featb, WallT, b_all, nullptr, nullptr, qkv, NPTS, 1024, DP_, 1024);

    // fp8 gather buffer from the kv region
    kv8_kernel<<<dim3(NPTS * 64 / 256), blk, 0, stream>>>(qkv, kv8);

    // fused attention -> ab = [hbar | rbar]
    attn_kernel<<<dim3(NPTS / 4), blk, 0, stream>>>(xyz, qkv, kv8, idx,
                                                    fd1_w, fd1_b, fd2_b, ab);

    // out = ab @ bt2^T + bias2 + features, stored TRANSPOSED directly to d_out
    gemm_f16_kernel<<<dim3(1, NPTS / 128), blk, 0, stream>>>(
        ab, bt2, bias2, features, out, nullptr, NPTS, DP_, 512, DP_);

    (void)in_sizes; (void)n_in; (void)out_size; (void)ws_size;
}